// Round 1
// baseline (86.606 us; speedup 1.0000x reference)
//
#include <hip/hip_runtime.h>
#include <math.h>

#define BB 4
#define NN 256
#define FCH 512
#define GCH 256
#define HID 128

// ---------------- kernel 1: row projection  out[row,:] = in[row,:] @ W + b ----------------
// grid = B*N blocks, block = 128 threads (one per output channel)
__global__ __launch_bounds__(128) void proj_kernel(const float* __restrict__ in,
                                                   const float* __restrict__ W,
                                                   const float* __restrict__ bias,
                                                   float* __restrict__ out,
                                                   int in_ch) {
    extern __shared__ float srow[];
    const int row = blockIdx.x;
    const int t = threadIdx.x;
    const float* irow = in + (size_t)row * in_ch;
    for (int c = t; c < in_ch; c += 128) srow[c] = irow[c];
    __syncthreads();
    float acc = bias[t];
    #pragma unroll 4
    for (int c = 0; c < in_ch; ++c) acc = fmaf(srow[c], W[c * HID + t], acc);
    out[(size_t)row * HID + t] = acc;
}

// ---------------- kernel 2: pre-contract mixing vectors ----------------
// cf_vec[h] = sum_k a_w[k] * Cf[k,h];  cg_vec likewise;  cst = a_w . (cf_b + cg_b)
__global__ __launch_bounds__(128) void mix_kernel(const float* __restrict__ Cf,
                                                  const float* __restrict__ cf_b,
                                                  const float* __restrict__ Cg,
                                                  const float* __restrict__ cg_b,
                                                  const float* __restrict__ a_w,
                                                  float* __restrict__ cf_vec,
                                                  float* __restrict__ cg_vec,
                                                  float* __restrict__ cst) {
    const int t = threadIdx.x;  // 0..127
    float accf = 0.f, accg = 0.f;
    for (int k = 0; k < HID; ++k) {
        const float a = a_w[k];
        accf = fmaf(a, Cf[k * HID + t], accf);
        accg = fmaf(a, Cg[k * HID + t], accg);
    }
    cf_vec[t] = accf;
    cg_vec[t] = accg;
    if (t == 0) {
        float c = 0.f;
        for (int k = 0; k < HID; ++k) c = fmaf(a_w[k], cf_b[k] + cg_b[k], c);
        *cst = c;
    }
}

// ---------------- kernel 3: fused att + masked softmax ----------------
// grid = B*N blocks (one per output row), block = 256 threads (one per m)
__global__ __launch_bounds__(256) void att_kernel(const float* __restrict__ pf,
                                                  const float* __restrict__ pg,
                                                  const float* __restrict__ adj,
                                                  const float* __restrict__ cf_vec,
                                                  const float* __restrict__ cg_vec,
                                                  const float* __restrict__ cst,
                                                  float* __restrict__ out) {
    const int bn = blockIdx.x;
    const int b = bn >> 8;
    const int n = bn & 255;
    const int m = threadIdx.x;

    __shared__ float uf[HID], ug[HID], scf[HID], scg[HID];
    __shared__ float redbuf[4];

    if (m < HID) {
        uf[m]  = pf[((size_t)b * NN + n) * HID + m];
        scf[m] = cf_vec[m];
    } else {
        const int h = m - HID;
        ug[h]  = pg[((size_t)b * NN + n) * HID + h];
        scg[h] = cg_vec[h];
    }
    __syncthreads();

    const float4* vf = (const float4*)(pf + ((size_t)b * NN + m) * HID);
    const float4* vg = (const float4*)(pg + ((size_t)b * NN + m) * HID);

    float numf = 0.f, denf = 0.f, numg = 0.f, deng = 0.f;
    #pragma unroll
    for (int i = 0; i < HID / 4; ++i) {
        float4 v = vf[i];
        float p0 = uf[4 * i + 0] * v.x;
        float p1 = uf[4 * i + 1] * v.y;
        float p2 = uf[4 * i + 2] * v.z;
        float p3 = uf[4 * i + 3] * v.w;
        numf = fmaf(p0, scf[4 * i + 0], numf);
        numf = fmaf(p1, scf[4 * i + 1], numf);
        numf = fmaf(p2, scf[4 * i + 2], numf);
        numf = fmaf(p3, scf[4 * i + 3], numf);
        denf = fmaf(p0, p0, denf);
        denf = fmaf(p1, p1, denf);
        denf = fmaf(p2, p2, denf);
        denf = fmaf(p3, p3, denf);
    }
    #pragma unroll
    for (int i = 0; i < HID / 4; ++i) {
        float4 v = vg[i];
        float p0 = ug[4 * i + 0] * v.x;
        float p1 = ug[4 * i + 1] * v.y;
        float p2 = ug[4 * i + 2] * v.z;
        float p3 = ug[4 * i + 3] * v.w;
        numg = fmaf(p0, scg[4 * i + 0], numg);
        numg = fmaf(p1, scg[4 * i + 1], numg);
        numg = fmaf(p2, scg[4 * i + 2], numg);
        numg = fmaf(p3, scg[4 * i + 3], numg);
        deng = fmaf(p0, p0, deng);
        deng = fmaf(p1, p1, deng);
        deng = fmaf(p2, p2, deng);
        deng = fmaf(p3, p3, deng);
    }

    float att = numf / fmaxf(sqrtf(denf), 1e-12f)
              + numg / fmaxf(sqrtf(deng), 1e-12f)
              + *cst;

    const float a = adj[((size_t)b * NN + n) * NN + m];
    if (a == 0.0f) att += -1e22f;

    // ---- block softmax over 256 threads (4 waves of 64) ----
    const int lane = m & 63;
    const int wid  = m >> 6;

    float mx = att;
    #pragma unroll
    for (int off = 1; off < 64; off <<= 1) mx = fmaxf(mx, __shfl_xor(mx, off, 64));
    if (lane == 0) redbuf[wid] = mx;
    __syncthreads();
    mx = fmaxf(fmaxf(redbuf[0], redbuf[1]), fmaxf(redbuf[2], redbuf[3]));
    __syncthreads();

    const float e = __expf(att - mx);

    float sm = e;
    #pragma unroll
    for (int off = 1; off < 64; off <<= 1) sm += __shfl_xor(sm, off, 64);
    if (lane == 0) redbuf[wid] = sm;
    __syncthreads();
    sm = redbuf[0] + redbuf[1] + redbuf[2] + redbuf[3];

    out[((size_t)b * NN + n) * NN + m] = e / sm;
}

extern "C" void kernel_launch(void* const* d_in, const int* in_sizes, int n_in,
                              void* d_out, int out_size, void* d_ws, size_t ws_size,
                              hipStream_t stream) {
    const float* feat  = (const float*)d_in[0];
    const float* gfeat = (const float*)d_in[1];
    const float* adj   = (const float*)d_in[2];
    const float* Wf    = (const float*)d_in[3];
    const float* bf    = (const float*)d_in[4];
    const float* Wg    = (const float*)d_in[5];
    const float* bg    = (const float*)d_in[6];
    const float* Cf    = (const float*)d_in[7];
    const float* cf_b  = (const float*)d_in[8];
    const float* Cg    = (const float*)d_in[9];
    const float* cg_b  = (const float*)d_in[10];
    const float* a_w   = (const float*)d_in[11];
    float* out = (float*)d_out;

    float* pf  = (float*)d_ws;                      // B*N*HID
    float* pg  = pf + (size_t)BB * NN * HID;        // B*N*HID
    float* cfv = pg + (size_t)BB * NN * HID;        // HID
    float* cgv = cfv + HID;                         // HID
    float* cst = cgv + HID;                         // 1

    proj_kernel<<<BB * NN, 128, FCH * sizeof(float), stream>>>(feat, Wf, bf, pf, FCH);
    proj_kernel<<<BB * NN, 128, GCH * sizeof(float), stream>>>(gfeat, Wg, bg, pg, GCH);
    mix_kernel<<<1, 128, 0, stream>>>(Cf, cf_b, Cg, cg_b, a_w, cfv, cgv, cst);
    att_kernel<<<BB * NN, 256, 0, stream>>>(pf, pg, adj, cfv, cgv, cst, out);
}

// Round 2
// 31.815 us; speedup vs baseline: 2.7222x; 2.7222x over previous
//
#include <hip/hip_runtime.h>
#include <math.h>

#define BB 4
#define NN 256
#define FCH 512
#define GCH 256
#define HID 128
#define ROWS 1024        // BB*NN
#define RPB 4            // rows per proj block
#define TN 4             // n-rows per att block

// ---------------- kernel 1: fused projection (f and g), transposed output ----------------
// out_T[h][row] = sum_c in[row][c]*W[c][h] + b[h]
// grid = (ROWS/RPB)*2 blocks, block = 512 threads = 128 ch x 4 k-split
__global__ __launch_bounds__(512) void proj_fg_kernel(const float* __restrict__ feat,
                                                      const float* __restrict__ gfeat,
                                                      const float* __restrict__ Wf,
                                                      const float* __restrict__ bf,
                                                      const float* __restrict__ Wg,
                                                      const float* __restrict__ bg,
                                                      float* __restrict__ pfT,
                                                      float* __restrict__ pgT) {
    __shared__ __align__(16) float srow[RPB * FCH];      // 8 KB max
    __shared__ float partial[4 * RPB * HID];             // 8 KB
    const int t = threadIdx.x;
    const bool isF = blockIdx.x < (ROWS / RPB);
    const int blk = isF ? blockIdx.x : blockIdx.x - (ROWS / RPB);
    const int r0 = blk * RPB;
    const int in_ch = isF ? FCH : GCH;
    const float* __restrict__ in = isF ? feat : gfeat;
    const float* __restrict__ W = isF ? Wf : Wg;
    const float* __restrict__ bias = isF ? bf : bg;
    float* __restrict__ dst = isF ? pfT : pgT;

    const int tot = RPB * in_ch;
    for (int idx = t; idx < tot; idx += 512)
        srow[idx] = in[(size_t)r0 * in_ch + idx];
    __syncthreads();

    const int ch = t & (HID - 1);
    const int kq = t >> 7;           // 0..3
    const int cpk = in_ch >> 2;      // 128 (f) or 64 (g)
    const int cbase = kq * cpk;

    float a0 = 0.f, a1 = 0.f, a2 = 0.f, a3 = 0.f;
    #pragma unroll 4
    for (int cc = 0; cc < cpk; cc += 4) {
        const int c = cbase + cc;
        const float w0 = W[(c + 0) * HID + ch];
        const float w1 = W[(c + 1) * HID + ch];
        const float w2 = W[(c + 2) * HID + ch];
        const float w3 = W[(c + 3) * HID + ch];
        const float4 s0 = *(const float4*)&srow[0 * in_ch + c];
        const float4 s1 = *(const float4*)&srow[1 * in_ch + c];
        const float4 s2 = *(const float4*)&srow[2 * in_ch + c];
        const float4 s3 = *(const float4*)&srow[3 * in_ch + c];
        a0 = fmaf(s0.x, w0, a0); a0 = fmaf(s0.y, w1, a0); a0 = fmaf(s0.z, w2, a0); a0 = fmaf(s0.w, w3, a0);
        a1 = fmaf(s1.x, w0, a1); a1 = fmaf(s1.y, w1, a1); a1 = fmaf(s1.z, w2, a1); a1 = fmaf(s1.w, w3, a1);
        a2 = fmaf(s2.x, w0, a2); a2 = fmaf(s2.y, w1, a2); a2 = fmaf(s2.z, w2, a2); a2 = fmaf(s2.w, w3, a2);
        a3 = fmaf(s3.x, w0, a3); a3 = fmaf(s3.y, w1, a3); a3 = fmaf(s3.z, w2, a3); a3 = fmaf(s3.w, w3, a3);
    }
    partial[(kq * RPB + 0) * HID + ch] = a0;
    partial[(kq * RPB + 1) * HID + ch] = a1;
    partial[(kq * RPB + 2) * HID + ch] = a2;
    partial[(kq * RPB + 3) * HID + ch] = a3;
    __syncthreads();

    const int j = t >> 7;            // 0..3
    const int ch2 = t & (HID - 1);
    const float v = bias[ch2]
                  + partial[(0 * RPB + j) * HID + ch2]
                  + partial[(1 * RPB + j) * HID + ch2]
                  + partial[(2 * RPB + j) * HID + ch2]
                  + partial[(3 * RPB + j) * HID + ch2];
    dst[(size_t)ch2 * ROWS + (r0 + j)] = v;
}

// ---------------- kernel 2: fused mix + att + masked softmax ----------------
// att[n,m] = dot(u_f*scf, v_f)/max(||..||,eps) + g-part   (cst cancels in softmax)
// grid = BB*64 blocks (TN=4 rows each), block = 512 threads = 256 m x 2 h-halves
__global__ __launch_bounds__(512) void att_kernel(const float* __restrict__ pfT,
                                                  const float* __restrict__ pgT,
                                                  const float* __restrict__ adj,
                                                  const float* __restrict__ Cf,
                                                  const float* __restrict__ Cg,
                                                  const float* __restrict__ a_w,
                                                  float* __restrict__ out) {
    __shared__ float scf[HID], scg[HID];
    __shared__ __align__(16) float ufc[TN][HID];
    __shared__ __align__(16) float uf2[TN][HID];
    __shared__ __align__(16) float ugc[TN][HID];
    __shared__ __align__(16) float ug2[TN][HID];
    __shared__ float hsred[16][NN];          // 16 KB
    __shared__ float red[2][4][TN];

    const int t = threadIdx.x;
    const int b = blockIdx.x >> 6;
    const int n0 = (blockIdx.x & 63) * TN;

    // phase 0: pre-contract scf[h] = sum_k a_w[k]*Cf[k][h], scg likewise
    if (t < HID) {
        float s = 0.f;
        for (int k = 0; k < HID; ++k) s = fmaf(a_w[k], Cf[k * HID + t], s);
        scf[t] = s;
    } else if (t < 2 * HID) {
        const int h = t - HID;
        float s = 0.f;
        for (int k = 0; k < HID; ++k) s = fmaf(a_w[k], Cg[k * HID + h], s);
        scg[h] = s;
    }
    __syncthreads();

    // phase 1: stage u-row derived arrays (TN rows)
    {
        const int j = t >> 7;            // 0..3  (TN*HID == 512 == blockDim)
        const int h = t & (HID - 1);
        const float uf = pfT[(size_t)h * ROWS + b * NN + n0 + j];
        const float ug = pgT[(size_t)h * ROWS + b * NN + n0 + j];
        ufc[j][h] = uf * scf[h];
        uf2[j][h] = uf * uf;
        ugc[j][h] = ug * scg[h];
        ug2[j][h] = ug * ug;
    }
    __syncthreads();

    // phase 2: stream v coalesced from transposed layout; each thread owns one m, half of h
    const int m = t & (NN - 1);
    const int hs = t >> 8;               // 0/1
    float numf[TN] = {0.f, 0.f, 0.f, 0.f};
    float denf[TN] = {0.f, 0.f, 0.f, 0.f};
    float numg[TN] = {0.f, 0.f, 0.f, 0.f};
    float deng[TN] = {0.f, 0.f, 0.f, 0.f};
    const float* __restrict__ basef = pfT + (size_t)(hs * 64) * ROWS + b * NN + m;
    const float* __restrict__ baseg = pgT + (size_t)(hs * 64) * ROWS + b * NN + m;

    #pragma unroll 4
    for (int h4 = 0; h4 < 64; h4 += 4) {
        const float vf0 = basef[(size_t)(h4 + 0) * ROWS];
        const float vf1 = basef[(size_t)(h4 + 1) * ROWS];
        const float vf2 = basef[(size_t)(h4 + 2) * ROWS];
        const float vf3 = basef[(size_t)(h4 + 3) * ROWS];
        const float vg0 = baseg[(size_t)(h4 + 0) * ROWS];
        const float vg1 = baseg[(size_t)(h4 + 1) * ROWS];
        const float vg2 = baseg[(size_t)(h4 + 2) * ROWS];
        const float vg3 = baseg[(size_t)(h4 + 3) * ROWS];
        const float wf0 = vf0 * vf0, wf1 = vf1 * vf1, wf2 = vf2 * vf2, wf3 = vf3 * vf3;
        const float wg0 = vg0 * vg0, wg1 = vg1 * vg1, wg2 = vg2 * vg2, wg3 = vg3 * vg3;
        const int h = hs * 64 + h4;
        #pragma unroll
        for (int j = 0; j < TN; ++j) {
            const float4 c4 = *(const float4*)&ufc[j][h];
            const float4 q4 = *(const float4*)&uf2[j][h];
            numf[j] = fmaf(vf0, c4.x, numf[j]); numf[j] = fmaf(vf1, c4.y, numf[j]);
            numf[j] = fmaf(vf2, c4.z, numf[j]); numf[j] = fmaf(vf3, c4.w, numf[j]);
            denf[j] = fmaf(wf0, q4.x, denf[j]); denf[j] = fmaf(wf1, q4.y, denf[j]);
            denf[j] = fmaf(wf2, q4.z, denf[j]); denf[j] = fmaf(wf3, q4.w, denf[j]);
            const float4 d4 = *(const float4*)&ugc[j][h];
            const float4 r4 = *(const float4*)&ug2[j][h];
            numg[j] = fmaf(vg0, d4.x, numg[j]); numg[j] = fmaf(vg1, d4.y, numg[j]);
            numg[j] = fmaf(vg2, d4.z, numg[j]); numg[j] = fmaf(vg3, d4.w, numg[j]);
            deng[j] = fmaf(wg0, r4.x, deng[j]); deng[j] = fmaf(wg1, r4.y, deng[j]);
            deng[j] = fmaf(wg2, r4.z, deng[j]); deng[j] = fmaf(wg3, r4.w, deng[j]);
        }
    }

    // h-split reduce
    if (hs == 1) {
        #pragma unroll
        for (int j = 0; j < TN; ++j) {
            hsred[j][m] = numf[j];
            hsred[4 + j][m] = denf[j];
            hsred[8 + j][m] = numg[j];
            hsred[12 + j][m] = deng[j];
        }
    }
    __syncthreads();

    float att[TN], e[TN];
    const int lane = t & 63;
    const int wid = t >> 6;              // 0..3 when hs==0
    if (hs == 0) {
        #pragma unroll
        for (int j = 0; j < TN; ++j) {
            const float nf = numf[j] + hsred[j][m];
            const float df = denf[j] + hsred[4 + j][m];
            const float ng = numg[j] + hsred[8 + j][m];
            const float dg = deng[j] + hsred[12 + j][m];
            float a = nf / fmaxf(sqrtf(df), 1e-12f) + ng / fmaxf(sqrtf(dg), 1e-12f);
            const float ad = adj[((size_t)(b * NN + n0 + j)) * NN + m];
            att[j] = (ad == 0.f) ? (a - 1e22f) : a;
        }
        float mx[TN];
        #pragma unroll
        for (int j = 0; j < TN; ++j) mx[j] = att[j];
        #pragma unroll
        for (int off = 1; off < 64; off <<= 1) {
            #pragma unroll
            for (int j = 0; j < TN; ++j) mx[j] = fmaxf(mx[j], __shfl_xor(mx[j], off, 64));
        }
        if (lane == 0) {
            #pragma unroll
            for (int j = 0; j < TN; ++j) red[0][wid][j] = mx[j];
        }
    }
    __syncthreads();
    if (hs == 0) {
        float sm[TN];
        #pragma unroll
        for (int j = 0; j < TN; ++j) {
            const float M = fmaxf(fmaxf(red[0][0][j], red[0][1][j]),
                                  fmaxf(red[0][2][j], red[0][3][j]));
            e[j] = __expf(att[j] - M);
            sm[j] = e[j];
        }
        #pragma unroll
        for (int off = 1; off < 64; off <<= 1) {
            #pragma unroll
            for (int j = 0; j < TN; ++j) sm[j] += __shfl_xor(sm[j], off, 64);
        }
        if (lane == 0) {
            #pragma unroll
            for (int j = 0; j < TN; ++j) red[1][wid][j] = sm[j];
        }
    }
    __syncthreads();
    if (hs == 0) {
        #pragma unroll
        for (int j = 0; j < TN; ++j) {
            const float S = red[1][0][j] + red[1][1][j] + red[1][2][j] + red[1][3][j];
            out[((size_t)(b * NN + n0 + j)) * NN + m] = e[j] / S;
        }
    }
}

extern "C" void kernel_launch(void* const* d_in, const int* in_sizes, int n_in,
                              void* d_out, int out_size, void* d_ws, size_t ws_size,
                              hipStream_t stream) {
    const float* feat  = (const float*)d_in[0];
    const float* gfeat = (const float*)d_in[1];
    const float* adj   = (const float*)d_in[2];
    const float* Wf    = (const float*)d_in[3];
    const float* bf    = (const float*)d_in[4];
    const float* Wg    = (const float*)d_in[5];
    const float* bg    = (const float*)d_in[6];
    const float* Cf    = (const float*)d_in[7];
    const float* Cg    = (const float*)d_in[9];
    const float* a_w   = (const float*)d_in[11];
    float* out = (float*)d_out;

    float* pfT = (float*)d_ws;                 // [HID][ROWS] = 512 KB
    float* pgT = pfT + (size_t)HID * ROWS;     // [HID][ROWS] = 512 KB

    proj_fg_kernel<<<(ROWS / RPB) * 2, 512, 0, stream>>>(feat, gfeat, Wf, bf, Wg, bg, pfT, pgT);
    att_kernel<<<BB * 64, 512, 0, stream>>>(pfT, pgT, adj, Cf, Cg, a_w, out);
}